// Round 19
// baseline (179.765 us; speedup 1.0000x reference)
//
#include <hip/hip_runtime.h>
#include <hip/hip_bf16.h>

#define N_ATOMS 8192
#define N_PAIR  131072
#define F       128
#define N_HEAD  8
#define FH      16
#define N_DEG   3
#define M_TOT   15
#define K_RBF   32
#define H_FILT  64
#define FILT_OUT 768
#define NDH     24   // N_DEG * N_HEAD
#define ATB     2    // atoms per aggr block (grid 4096)
#define CHUNK   32   // pairs per aggr staging chunk

typedef __attribute__((ext_vector_type(8))) unsigned short u16x8;
typedef __attribute__((ext_vector_type(4))) unsigned short u16x4;

#if defined(__has_builtin)
# if __has_builtin(__builtin_amdgcn_fdot2_f32_bf16)
#  define HAVE_BF16_DOT2 1
# endif
#endif
#ifndef HAVE_BF16_DOT2
# define HAVE_BF16_DOT2 0
#endif

__device__ __forceinline__ float bf2f(unsigned short u) {
    return __uint_as_float(((unsigned)u) << 16);
}
__device__ __forceinline__ unsigned short f2bfbits(float f) {
    __hip_bfloat16 b = __float2bfloat16(f);
    return *reinterpret_cast<unsigned short*>(&b);
}

#if HAVE_BF16_DOT2
typedef __bf16 bf16x2 __attribute__((ext_vector_type(2)));
__device__ __forceinline__ float dot8d(uint4 g, uint4 h, float c) {
    union { unsigned u; bf16x2 v; } a, b;
    a.u = g.x; b.u = h.x; c = __builtin_amdgcn_fdot2_f32_bf16(a.v, b.v, c, false);
    a.u = g.y; b.u = h.y; c = __builtin_amdgcn_fdot2_f32_bf16(a.v, b.v, c, false);
    a.u = g.z; b.u = h.z; c = __builtin_amdgcn_fdot2_f32_bf16(a.v, b.v, c, false);
    a.u = g.w; b.u = h.w; c = __builtin_amdgcn_fdot2_f32_bf16(a.v, b.v, c, false);
    return c;
}
#endif

// ---------------- K_front: wc | seg | hist | xbf | h1 (independent work, one launch) ----------------
__global__ __launch_bounds__(256) void k_front(
    const int* __restrict__ idx_i, const int* __restrict__ idx_j,
    int* __restrict__ row_start, int* __restrict__ counts,
    const float* __restrict__ WQ, const float* __restrict__ WK,
    const float* __restrict__ avec, const float* __restrict__ W2,
    const float* __restrict__ b2, float* __restrict__ Wc, float* __restrict__ bc,
    const float* __restrict__ rbf, const float* __restrict__ W1,
    const float* __restrict__ b1, unsigned short* __restrict__ h1,
    const float* __restrict__ x, unsigned short* __restrict__ xbf)
{
    __shared__ __align__(16) char smem[16896];
    int tid = threadIdx.x;
    int bx = blockIdx.x;
    if (bx < 48) {                       // ---- combined weights (wc) ----
        float* w2s = (float*)smem;              // [64][16]
        float* wsm = (float*)(smem + 4096);     // [16][16]
        float* as  = (float*)(smem + 5120);     // [16]
        float* b2s = (float*)(smem + 5184);     // [16]
        int side = bx / NDH, dh = bx % NDH;
        int d = dh >> 3, h = dh & 7;
        int colbase = d * 256 + h * 32 + side * 16;
        const float* W = (side == 0) ? WQ : WK;
        for (int e = tid; e < 1024; e += 256)
            w2s[e] = W2[(e >> 4) * FILT_OUT + colbase + (e & 15)];
        wsm[tid] = W[((d * 8 + h) * 16) * 16 + tid];
        if (tid < 16) { as[tid] = avec[dh * 32 + side * 16 + tid]; b2s[tid] = b2[colbase + tid]; }
        __syncthreads();
        for (int o = tid; o < 1024; o += 256) {
            int k = o >> 4, j = o & 15;
            float s = 0.f;
            #pragma unroll
            for (int c = 0; c < 16; ++c) s += w2s[k * 16 + c] * as[c] * wsm[c * 16 + j];
            Wc[((size_t)bx * 64 + k) * 16 + j] = s;
        }
        if (tid < 16) {
            float s = 0.f;
            #pragma unroll
            for (int c = 0; c < 16; ++c) s += b2s[c] * as[c] * wsm[c * 16 + tid];
            bc[bx * 16 + tid] = s;
        }
        return;
    }
    bx -= 48;
    if (bx < 512) {                      // ---- segment starts (idx_i sorted) ----
        int p = bx * 256 + tid;
        int ii = idx_i[p];
        int prev = (p == 0) ? -1 : idx_i[p - 1];
        for (int a = prev + 1; a <= ii; ++a) row_start[a] = p;
        if (p == N_PAIR - 1) {
            for (int a = ii + 1; a <= N_ATOMS; ++a) row_start[a] = N_PAIR;
        }
        return;
    }
    bx -= 512;
    if (bx < 512) {                      // ---- histogram of idx_j ----
        int p = bx * 256 + tid;
        atomicAdd(&counts[idx_j[p]], 1);
        return;
    }
    bx -= 512;
    if (bx < 512) {                      // ---- x -> bf16 copy (1M elems, 8/thread) ----
        size_t e0 = ((size_t)bx * 256 + tid) * 8;
        float4 v0 = *reinterpret_cast<const float4*>(x + e0);
        float4 v1 = *reinterpret_cast<const float4*>(x + e0 + 4);
        u16x8 o;
        o[0] = f2bfbits(v0.x); o[1] = f2bfbits(v0.y);
        o[2] = f2bfbits(v0.z); o[3] = f2bfbits(v0.w);
        o[4] = f2bfbits(v1.x); o[5] = f2bfbits(v1.y);
        o[6] = f2bfbits(v1.z); o[7] = f2bfbits(v1.w);
        *reinterpret_cast<u16x8*>(xbf + e0) = o;
        return;
    }
    bx -= 512;
    {                                    // ---- h1 = silu(rbf @ W1 + b1) ----
        float* w1s  = (float*)smem;             // [32][64]
        float* b1s  = (float*)(smem + 8192);    // [64]
        float* rbfs = (float*)(smem + 8448);    // [64][33]
        int p0 = bx * 64;
        for (int e = tid; e < K_RBF * H_FILT; e += 256) w1s[e] = W1[e];
        if (tid < H_FILT) b1s[tid] = b1[tid];
        for (int e = tid; e < 64 * K_RBF; e += 256)
            rbfs[(e >> 5) * 33 + (e & 31)] = rbf[(size_t)p0 * K_RBF + e];
        __syncthreads();
        int pp = tid >> 2;
        int kbase = (tid & 3) * 16;
        float acc[16];
        #pragma unroll
        for (int q = 0; q < 16; ++q) acc[q] = b1s[kbase + q];
        for (int c = 0; c < K_RBF; ++c) {
            float r = rbfs[pp * 33 + c];
            #pragma unroll
            for (int q = 0; q < 16; ++q) acc[q] += r * w1s[c * 64 + kbase + q];
        }
        u16x8 o0, o1;
        #pragma unroll
        for (int q = 0; q < 8; ++q) {
            float s0 = acc[q];     o0[q] = f2bfbits(s0 / (1.f + __expf(-s0)));
            float s1 = acc[q + 8]; o1[q] = f2bfbits(s1 / (1.f + __expf(-s1)));
        }
        unsigned short* hp = h1 + (size_t)(p0 + pp) * 64 + kbase;
        *reinterpret_cast<u16x8*>(hp) = o0;
        *reinterpret_cast<u16x8*>(hp + 8) = o1;
    }
}

// ---------------- exclusive scan of 8192 counts (1 block) ----------------
__global__ __launch_bounds__(1024) void k_scan(const int* __restrict__ counts,
                                               int* __restrict__ offsets) {
    __shared__ int ts[1024];
    int tid = threadIdx.x;
    int base = tid * 8;
    int v[8]; int tot = 0;
    #pragma unroll
    for (int q = 0; q < 8; ++q) { v[q] = counts[base + q]; tot += v[q]; }
    ts[tid] = tot; __syncthreads();
    for (int off = 1; off < 1024; off <<= 1) {
        int t2 = (tid >= off) ? ts[tid - off] : 0;
        __syncthreads();
        ts[tid] += t2;
        __syncthreads();
    }
    int excl = ts[tid] - tot;
    #pragma unroll
    for (int q = 0; q < 8; ++q) { offsets[base + q] = excl; excl += v[q]; }
    if (tid == 1023) offsets[N_ATOMS] = ts[1023];
}

// ---------------- placement: sorted pair ids per j-bucket + rank ----------------
__global__ void k_place(const int* __restrict__ idx_j, const int* __restrict__ offsets,
                        int* __restrict__ cnt2, int* __restrict__ sorted,
                        int* __restrict__ rank) {
    int p = blockIdx.x * 256 + threadIdx.x;
    if (p < N_PAIR) {
        int j = idx_j[p];
        int pos = offsets[j] + atomicAdd(&cnt2[j], 1);
        sorted[pos] = p;
        rank[p] = pos;
    }
}

// ---------------- K_gfused: x -> Gq/Gk/bq/bk directly ----------------
__global__ __launch_bounds__(256) void k_gfused(
    const float* __restrict__ x, const float* __restrict__ Wc,
    const float* __restrict__ bc,
    __hip_bfloat16* __restrict__ Gq, __hip_bfloat16* __restrict__ Gk,
    float* __restrict__ bq, float* __restrict__ bk)
{
    int bx = blockIdx.x;             // 128 blocks of 64 atoms
    int by = blockIdx.y;             // 0..47: side, dh
    int side = by / NDH, dh = by % NDH;
    int h = dh & 7;
    int n0 = bx * 64;
    __shared__ float xh[64][17];     // padded: conflict-free per-at reads
    __shared__ float bcs[16];
    int tid = threadIdx.x;
    for (int e = tid; e < 64 * 16; e += 256)
        xh[e >> 4][e & 15] = x[(size_t)(n0 + (e >> 4)) * F + h * 16 + (e & 15)];
    if (tid < 16) bcs[tid] = bc[by * 16 + tid];
    int k = tid & 63, wv = tid >> 6;
    float wcr[16];
    const float* wp = Wc + ((size_t)by * 64 + k) * 16;
    #pragma unroll
    for (int j = 0; j < 16; ++j) wcr[j] = wp[j];
    __syncthreads();
    __hip_bfloat16* G = (side == 0) ? Gq : Gk;
    #pragma unroll 4
    for (int it = 0; it < 16; ++it) {
        int at = wv * 16 + it;
        float acc = 0.f;
        #pragma unroll
        for (int j = 0; j < 16; ++j) acc += wcr[j] * xh[at][j];  // broadcast reads
        G[(size_t)(n0 + at) * 1536 + dh * 64 + k] = __float2bfloat16(acc);
    }
    if (tid < 64) {
        float* B = (side == 0) ? bq : bk;
        float s = 0.f;
        #pragma unroll
        for (int j = 0; j < 16; ++j) s += bcs[j] * xh[tid][j];
        B[(n0 + tid) * NDH + dh] = s;
    }
}

#if !HAVE_BF16_DOT2
// ------- fallback helpers: f32 LDS staging + manual unpack dot -------
__device__ __forceinline__ void stage_h1f(float (*h1f)[72],
                                          const unsigned short* __restrict__ h1,
                                          const int* ps, int tid) {
    for (int e = tid; e < 64 * 32; e += 256) {
        int slot = e >> 5, kp = e & 31;
        unsigned d = *reinterpret_cast<const unsigned*>(h1 + (size_t)ps[slot] * 64 + kp * 2);
        float2 f;
        f.x = __uint_as_float(d << 16);
        f.y = __uint_as_float(d & 0xFFFF0000u);
        *reinterpret_cast<float2*>(&h1f[slot][kp * 2]) = f;
    }
}
__device__ __forceinline__ float dot8u(uint4 g, float4 h0, float4 h1v) {
    float p;
    p  = __uint_as_float(g.x << 16) * h0.x + __uint_as_float(g.x & 0xFFFF0000u) * h0.y;
    p += __uint_as_float(g.y << 16) * h0.z + __uint_as_float(g.y & 0xFFFF0000u) * h0.w;
    p += __uint_as_float(g.z << 16) * h1v.x + __uint_as_float(g.z & 0xFFFF0000u) * h1v.y;
    p += __uint_as_float(g.w << 16) * h1v.z + __uint_as_float(g.w & 0xFFFF0000u) * h1v.w;
    return p;
}
#endif

// ---------------- K2c: K-side alpha, seg-parallel, 4-wide ILP ----------------
__global__ __launch_bounds__(256) void k_alphak3(
    const int* __restrict__ sorted, const int* __restrict__ idx_j,
    const unsigned short* __restrict__ h1,
    const __hip_bfloat16* __restrict__ Gk, const float* __restrict__ bk,
    unsigned short* __restrict__ alphaKs)
{
#if HAVE_BF16_DOT2
    __shared__ __align__(16) unsigned short h1s[64][72]; // 9 KB
#else
    __shared__ __align__(16) float h1f[64][72];          // 18 KB
#endif
    __shared__ float als[64][24];
    __shared__ int ps[64];
    __shared__ int js[64];
    int tid = threadIdx.x;
    int c0 = blockIdx.x * 64;
    if (tid < 64) {
        int pid = sorted[c0 + tid];
        ps[tid] = pid;
        js[tid] = idx_j[pid];
    }
    __syncthreads();
#if HAVE_BF16_DOT2
    for (int e = tid; e < 64 * 8; e += 256) {
        int slot = e >> 3, seg = e & 7;
        *reinterpret_cast<u16x8*>(&h1s[slot][seg * 8]) =
            *reinterpret_cast<const u16x8*>(h1 + (size_t)ps[slot] * 64 + seg * 8);
    }
#else
    stage_h1f(h1f, h1, ps, tid);
#endif
    __syncthreads();
    const unsigned short* GkU = reinterpret_cast<const unsigned short*>(Gk);
    int seg = tid & 7;
    for (int t = 0; t < 12; ++t) {
        int base = t * 1024 + tid;
        int ds0 = base >> 3, ds1 = (base + 256) >> 3,
            ds2 = (base + 512) >> 3, ds3 = (base + 768) >> 3;
        int s0 = ds0 / 24, d0 = ds0 - s0 * 24;
        int s1 = ds1 / 24, d1 = ds1 - s1 * 24;
        int s2 = ds2 / 24, d2 = ds2 - s2 * 24;
        int s3 = ds3 / 24, d3 = ds3 - s3 * 24;
        uint4 g0 = *reinterpret_cast<const uint4*>(GkU + (size_t)js[s0] * 1536 + d0 * 64 + seg * 8);
        uint4 g1 = *reinterpret_cast<const uint4*>(GkU + (size_t)js[s1] * 1536 + d1 * 64 + seg * 8);
        uint4 g2 = *reinterpret_cast<const uint4*>(GkU + (size_t)js[s2] * 1536 + d2 * 64 + seg * 8);
        uint4 g3 = *reinterpret_cast<const uint4*>(GkU + (size_t)js[s3] * 1536 + d3 * 64 + seg * 8);
#if HAVE_BF16_DOT2
        uint4 h0 = *reinterpret_cast<const uint4*>(&h1s[s0][seg * 8]);
        uint4 h1q = *reinterpret_cast<const uint4*>(&h1s[s1][seg * 8]);
        uint4 h2 = *reinterpret_cast<const uint4*>(&h1s[s2][seg * 8]);
        uint4 h3 = *reinterpret_cast<const uint4*>(&h1s[s3][seg * 8]);
        float p0 = dot8d(g0, h0, 0.f);
        float p1 = dot8d(g1, h1q, 0.f);
        float p2 = dot8d(g2, h2, 0.f);
        float p3 = dot8d(g3, h3, 0.f);
#else
        float p0 = dot8u(g0, *reinterpret_cast<const float4*>(&h1f[s0][seg * 8]),
                             *reinterpret_cast<const float4*>(&h1f[s0][seg * 8 + 4]));
        float p1 = dot8u(g1, *reinterpret_cast<const float4*>(&h1f[s1][seg * 8]),
                             *reinterpret_cast<const float4*>(&h1f[s1][seg * 8 + 4]));
        float p2 = dot8u(g2, *reinterpret_cast<const float4*>(&h1f[s2][seg * 8]),
                             *reinterpret_cast<const float4*>(&h1f[s2][seg * 8 + 4]));
        float p3 = dot8u(g3, *reinterpret_cast<const float4*>(&h1f[s3][seg * 8]),
                             *reinterpret_cast<const float4*>(&h1f[s3][seg * 8 + 4]));
#endif
        p0 += __shfl_xor(p0, 1); p1 += __shfl_xor(p1, 1);
        p2 += __shfl_xor(p2, 1); p3 += __shfl_xor(p3, 1);
        p0 += __shfl_xor(p0, 2); p1 += __shfl_xor(p1, 2);
        p2 += __shfl_xor(p2, 2); p3 += __shfl_xor(p3, 2);
        p0 += __shfl_xor(p0, 4); p1 += __shfl_xor(p1, 4);
        p2 += __shfl_xor(p2, 4); p3 += __shfl_xor(p3, 4);
        if (seg == 0) {
            als[s0][d0] = p0; als[s1][d1] = p1;
            als[s2][d2] = p2; als[s3][d3] = p3;
        }
    }
    __syncthreads();
    for (int e = tid; e < 64 * 24; e += 256) {
        int slot = e / 24, dh = e - slot * 24;
        float val = als[slot][dh] + bk[js[slot] * NDH + dh];
        alphaKs[(size_t)c0 * 24 + e] = f2bfbits(val);
    }
}

// ---------------- K2d: full alpha in p-order, seg-parallel, 4-wide ILP ----------------
// alphaF = (dotQ + bq + alphaKs[rank]) * phi * mask^2 * 0.25
__global__ __launch_bounds__(256) void k_alphaA3(
    const int* __restrict__ idx_i, const int* __restrict__ rank,
    const float* __restrict__ phi, const float* __restrict__ mask,
    const unsigned short* __restrict__ h1,
    const __hip_bfloat16* __restrict__ Gq, const float* __restrict__ bq,
    const unsigned short* __restrict__ alphaKs,
    float* __restrict__ alphaF)
{
#if HAVE_BF16_DOT2
    __shared__ __align__(16) unsigned short h1s[64][72];
#else
    __shared__ __align__(16) float h1f[64][72];
#endif
    __shared__ float als[64][24];
    __shared__ int is[64];
    __shared__ int rks[64];
    __shared__ float pms[64];
#if !HAVE_BF16_DOT2
    __shared__ int psn[64];
#endif
    int tid = threadIdx.x;
    int p0 = blockIdx.x * 64;
    if (tid < 64) {
        int p = p0 + tid;
        is[tid] = idx_i[p];
        rks[tid] = rank[p];
        float mk = mask[p];
        pms[tid] = phi[p] * mk * mk * 0.25f;
#if !HAVE_BF16_DOT2
        psn[tid] = p;
#endif
    }
    __syncthreads();
#if HAVE_BF16_DOT2
    for (int e = tid; e < 64 * 8; e += 256) {
        int slot = e >> 3, seg = e & 7;
        *reinterpret_cast<u16x8*>(&h1s[slot][seg * 8]) =
            *reinterpret_cast<const u16x8*>(h1 + (size_t)(p0 + slot) * 64 + seg * 8);
    }
#else
    stage_h1f(h1f, h1, psn, tid);
#endif
    __syncthreads();
    const unsigned short* GqU = reinterpret_cast<const unsigned short*>(Gq);
    int seg = tid & 7;
    for (int t = 0; t < 12; ++t) {
        int base = t * 1024 + tid;
        int ds0 = base >> 3, ds1 = (base + 256) >> 3,
            ds2 = (base + 512) >> 3, ds3 = (base + 768) >> 3;
        int s0 = ds0 / 24, d0 = ds0 - s0 * 24;
        int s1 = ds1 / 24, d1 = ds1 - s1 * 24;
        int s2 = ds2 / 24, d2 = ds2 - s2 * 24;
        int s3 = ds3 / 24, d3 = ds3 - s3 * 24;
        uint4 g0 = *reinterpret_cast<const uint4*>(GqU + (size_t)is[s0] * 1536 + d0 * 64 + seg * 8);
        uint4 g1 = *reinterpret_cast<const uint4*>(GqU + (size_t)is[s1] * 1536 + d1 * 64 + seg * 8);
        uint4 g2 = *reinterpret_cast<const uint4*>(GqU + (size_t)is[s2] * 1536 + d2 * 64 + seg * 8);
        uint4 g3 = *reinterpret_cast<const uint4*>(GqU + (size_t)is[s3] * 1536 + d3 * 64 + seg * 8);
#if HAVE_BF16_DOT2
        uint4 h0 = *reinterpret_cast<const uint4*>(&h1s[s0][seg * 8]);
        uint4 h1q = *reinterpret_cast<const uint4*>(&h1s[s1][seg * 8]);
        uint4 h2 = *reinterpret_cast<const uint4*>(&h1s[s2][seg * 8]);
        uint4 h3 = *reinterpret_cast<const uint4*>(&h1s[s3][seg * 8]);
        float p0v = dot8d(g0, h0, 0.f);
        float p1v = dot8d(g1, h1q, 0.f);
        float p2v = dot8d(g2, h2, 0.f);
        float p3v = dot8d(g3, h3, 0.f);
#else
        float p0v = dot8u(g0, *reinterpret_cast<const float4*>(&h1f[s0][seg * 8]),
                              *reinterpret_cast<const float4*>(&h1f[s0][seg * 8 + 4]));
        float p1v = dot8u(g1, *reinterpret_cast<const float4*>(&h1f[s1][seg * 8]),
                              *reinterpret_cast<const float4*>(&h1f[s1][seg * 8 + 4]));
        float p2v = dot8u(g2, *reinterpret_cast<const float4*>(&h1f[s2][seg * 8]),
                              *reinterpret_cast<const float4*>(&h1f[s2][seg * 8 + 4]));
        float p3v = dot8u(g3, *reinterpret_cast<const float4*>(&h1f[s3][seg * 8]),
                              *reinterpret_cast<const float4*>(&h1f[s3][seg * 8 + 4]));
#endif
        p0v += __shfl_xor(p0v, 1); p1v += __shfl_xor(p1v, 1);
        p2v += __shfl_xor(p2v, 1); p3v += __shfl_xor(p3v, 1);
        p0v += __shfl_xor(p0v, 2); p1v += __shfl_xor(p1v, 2);
        p2v += __shfl_xor(p2v, 2); p3v += __shfl_xor(p3v, 2);
        p0v += __shfl_xor(p0v, 4); p1v += __shfl_xor(p1v, 4);
        p2v += __shfl_xor(p2v, 4); p3v += __shfl_xor(p3v, 4);
        if (seg == 0) {
            als[s0][d0] = p0v; als[s1][d1] = p1v;
            als[s2][d2] = p2v; als[s3][d3] = p3v;
        }
    }
    __syncthreads();
    for (int e = tid; e < 64 * 24; e += 256) {
        int slot = e / 24, dh = e - slot * 24;
        float val = als[slot][dh] + bq[is[slot] * NDH + dh]
                  + bf2f(alphaKs[(size_t)rks[slot] * 24 + dh]);
        alphaF[(size_t)p0 * 24 + e] = val * pms[slot];
    }
}

// ---------------- K3: segment-sum, bf16 x gather (L2-resident table) ----------------
__global__ __launch_bounds__(256) void k_aggr11(
    const unsigned short* __restrict__ xbf, const float* __restrict__ sph,
    const int* __restrict__ idx_i, const int* __restrict__ idx_j,
    const float* __restrict__ alphaF,
    const int* __restrict__ row_start, float* __restrict__ out)
{
    int a0 = blockIdx.x * ATB;
    int tid = threadIdx.x;
    int f = tid & 127, grp = tid >> 7, h = f >> 4;

    __shared__ float alsT[CHUNK][8][4];  // 4 KB: [q][h][d]
    __shared__ float sls[CHUNK][16];     // 2 KB (padded)
    __shared__ int   iis[CHUNK];
    __shared__ int   jjs[CHUNK];
    __shared__ int   rs[ATB + 1];

    if (tid <= ATB) rs[tid] = row_start[a0 + tid];
    __syncthreads();
    int pstart = rs[0], pend = rs[ATB];

    float acc[8];
    #pragma unroll
    for (int m = 0; m < 8; ++m) acc[m] = 0.f;
    int cur = -1;

#define FLUSH(CUR)                                                        \
    { size_t ob = (size_t)(CUR) * (M_TOT * F) + f;                        \
      if (grp == 0) {                                                     \
          _Pragma("unroll")                                               \
          for (int m = 0; m < 8; ++m) out[ob + m * 128] = acc[m];         \
      } else {                                                            \
          _Pragma("unroll")                                               \
          for (int m = 0; m < 7; ++m) out[ob + (8 + m) * 128] = acc[m];   \
      } }

#define AGG_STEP(Q, XV)                                                   \
    { int ia = iis[Q];                                                    \
      if (ia != cur) {                                                    \
          if (cur >= 0) FLUSH(cur);                                       \
          cur = ia;                                                       \
          _Pragma("unroll")                                               \
          for (int m = 0; m < 8; ++m) acc[m] = 0.f;                       \
      }                                                                   \
      if (grp == 0) {                                                     \
          float2 t01 = *reinterpret_cast<const float2*>(&alsT[Q][h][0]);  \
          float t0 = t01.x * (XV);                                        \
          float t1 = t01.y * (XV);                                        \
          acc[0] += t0 * sls[Q][0];                                       \
          acc[1] += t0 * sls[Q][1];                                       \
          acc[2] += t0 * sls[Q][2];                                       \
          _Pragma("unroll")                                               \
          for (int m = 3; m < 8; ++m) acc[m] += t1 * sls[Q][m];           \
      } else {                                                            \
          float t2 = alsT[Q][h][2] * (XV);                                \
          _Pragma("unroll")                                               \
          for (int m = 0; m < 7; ++m) acc[m] += t2 * sls[Q][8 + m];       \
      } }

    for (int pc = pstart; pc < pend; pc += CHUNK) {
        int nb = min(CHUNK, pend - pc);
        __syncthreads();
        if (tid < nb) {
            int p = pc + tid;
            iis[tid] = idx_i[p];
            jjs[tid] = idx_j[p];
        }
        for (int e = tid; e < nb * 24; e += 256) {
            int q = e / 24, dh = e - q * 24;
            alsT[q][dh & 7][dh >> 3] = alphaF[(size_t)pc * 24 + e];
        }
        for (int e = tid; e < nb * 15; e += 256)
            sls[e / 15][e % 15] = sph[(size_t)pc * 15 + e];
        __syncthreads();
        float xa = 0.f, xb = 0.f, xc = 0.f, xd = 0.f;
        if (nb > 0) xa = bf2f(xbf[(size_t)jjs[0] * F + f]);
        if (nb > 1) xb = bf2f(xbf[(size_t)jjs[1] * F + f]);
        if (nb > 2) xc = bf2f(xbf[(size_t)jjs[2] * F + f]);
        if (nb > 3) xd = bf2f(xbf[(size_t)jjs[3] * F + f]);
        for (int qg = 0; qg < nb; qg += 4) {
            float ya = 0.f, yb = 0.f, yc = 0.f, yd = 0.f;
            int nq = qg + 4;
            if (nq < nb) {
                ya = bf2f(xbf[(size_t)jjs[nq] * F + f]);
                if (nq + 1 < nb) yb = bf2f(xbf[(size_t)jjs[nq + 1] * F + f]);
                if (nq + 2 < nb) yc = bf2f(xbf[(size_t)jjs[nq + 2] * F + f]);
                if (nq + 3 < nb) yd = bf2f(xbf[(size_t)jjs[nq + 3] * F + f]);
            }
            AGG_STEP(qg, xa);
            if (qg + 1 < nb) AGG_STEP(qg + 1, xb);
            if (qg + 2 < nb) AGG_STEP(qg + 2, xc);
            if (qg + 3 < nb) AGG_STEP(qg + 3, xd);
            xa = ya; xb = yb; xc = yc; xd = yd;
        }
    }
    if (cur >= 0) FLUSH(cur);
    // zero-fill atoms with no pairs
    for (int a = 0; a < ATB; ++a) {
        if (rs[a] == rs[a + 1]) {
            size_t ob = (size_t)(a0 + a) * (M_TOT * F) + f;
            if (grp == 0) {
                #pragma unroll
                for (int m = 0; m < 8; ++m) out[ob + m * 128] = 0.f;
            } else {
                #pragma unroll
                for (int m = 0; m < 7; ++m) out[ob + (8 + m) * 128] = 0.f;
            }
        }
    }
#undef AGG_STEP
#undef FLUSH
}

extern "C" void kernel_launch(void* const* d_in, const int* in_sizes, int n_in,
                              void* d_out, int out_size, void* d_ws, size_t ws_size,
                              hipStream_t stream) {
    const float* x     = (const float*)d_in[0];
    const float* rbf   = (const float*)d_in[1];
    const float* sph   = (const float*)d_in[2];
    const float* phi   = (const float*)d_in[3];
    const int*   idx_i = (const int*)d_in[4];
    const int*   idx_j = (const int*)d_in[5];
    const float* mask  = (const float*)d_in[6];
    const float* WQ    = (const float*)d_in[7];
    const float* WK    = (const float*)d_in[8];
    const float* av    = (const float*)d_in[9];
    const float* W1    = (const float*)d_in[10];
    const float* b1    = (const float*)d_in[11];
    const float* W2    = (const float*)d_in[12];
    const float* b2    = (const float*)d_in[13];
    float* out = (float*)d_out;
    char* ws = (char*)d_ws;

    // ws layout (bytes): as R15-R18 plus xbf (2 MB) at the tail
    __hip_bfloat16* Gq = (__hip_bfloat16*)(ws + 0);
    __hip_bfloat16* Gk = (__hip_bfloat16*)(ws + 25165824);
    float* alphaF = (float*)(ws + 25165824);       // aliases Gk (dead after k_alphak3)
    float* bq = (float*)(ws + 50331648);
    float* bk = (float*)(ws + 51118080);
    int* row_start = (int*)(ws + 51904512);
    int* counts    = (int*)(ws + 51937792);
    int* cnt2      = (int*)(ws + 51970560);
    int* offsets   = (int*)(ws + 52003328);
    int* sorted    = (int*)(ws + 52036608);
    int* rank      = (int*)(ws + 52560896);
    unsigned short* h1      = (unsigned short*)(ws + 53085184);
    unsigned short* alphaKs = (unsigned short*)(ws + 69862400);
    float* Wc = (float*)(ws + 76153856);
    float* bc = (float*)(ws + 76350464);
    unsigned short* xbf = (unsigned short*)(ws + 76356608);  // 2 MB -> ends 78453760

    hipMemsetAsync(ws + 51937792, 0, 65536, stream);
    // k_front: [0,48)=wc | [48,560)=seg | [560,1072)=hist | [1072,1584)=xbf | [1584,3632)=h1
    k_front<<<3632, 256, 0, stream>>>(idx_i, idx_j, row_start, counts,
                                      WQ, WK, av, W2, b2, Wc, bc,
                                      rbf, W1, b1, h1, x, xbf);
    k_scan<<<1, 1024, 0, stream>>>(counts, offsets);
    k_place<<<(N_PAIR + 255) / 256, 256, 0, stream>>>(idx_j, offsets, cnt2, sorted, rank);
    k_gfused<<<dim3(N_ATOMS / 64, 48), 256, 0, stream>>>(x, Wc, bc, Gq, Gk, bq, bk);
    k_alphak3<<<N_PAIR / 64, 256, 0, stream>>>(sorted, idx_j, h1, Gk, bk, alphaKs);
    k_alphaA3<<<N_PAIR / 64, 256, 0, stream>>>(idx_i, rank, phi, mask, h1, Gq, bq,
                                               alphaKs, alphaF);
    k_aggr11<<<N_ATOMS / ATB, 256, 0, stream>>>(xbf, sph, idx_i, idx_j, alphaF,
                                                row_start, out);
}

// Round 20
// 167.248 us; speedup vs baseline: 1.0748x; 1.0748x over previous
//
#include <hip/hip_runtime.h>
#include <hip/hip_bf16.h>

#define N_ATOMS 8192
#define N_PAIR  131072
#define F       128
#define N_HEAD  8
#define FH      16
#define N_DEG   3
#define M_TOT   15
#define K_RBF   32
#define H_FILT  64
#define FILT_OUT 768
#define NDH     24   // N_DEG * N_HEAD
#define ATB     2    // atoms per aggr block (grid 4096)

typedef __attribute__((ext_vector_type(8))) unsigned short u16x8;

#if defined(__has_builtin)
# if __has_builtin(__builtin_amdgcn_fdot2_f32_bf16)
#  define HAVE_BF16_DOT2 1
# endif
#endif
#ifndef HAVE_BF16_DOT2
# define HAVE_BF16_DOT2 0
#endif

__device__ __forceinline__ float bf2f(unsigned short u) {
    return __uint_as_float(((unsigned)u) << 16);
}
__device__ __forceinline__ unsigned short f2bfbits(float f) {
    __hip_bfloat16 b = __float2bfloat16(f);
    return *reinterpret_cast<unsigned short*>(&b);
}

#if HAVE_BF16_DOT2
typedef __bf16 bf16x2 __attribute__((ext_vector_type(2)));
__device__ __forceinline__ float dot8d(uint4 g, uint4 h, float c) {
    union { unsigned u; bf16x2 v; } a, b;
    a.u = g.x; b.u = h.x; c = __builtin_amdgcn_fdot2_f32_bf16(a.v, b.v, c, false);
    a.u = g.y; b.u = h.y; c = __builtin_amdgcn_fdot2_f32_bf16(a.v, b.v, c, false);
    a.u = g.z; b.u = h.z; c = __builtin_amdgcn_fdot2_f32_bf16(a.v, b.v, c, false);
    a.u = g.w; b.u = h.w; c = __builtin_amdgcn_fdot2_f32_bf16(a.v, b.v, c, false);
    return c;
}
#endif

// ---------------- K_front: wc | seg | hist | h1 (independent work, one launch) ----------------
__global__ __launch_bounds__(256) void k_front(
    const int* __restrict__ idx_i, const int* __restrict__ idx_j,
    int* __restrict__ row_start, int* __restrict__ counts,
    const float* __restrict__ WQ, const float* __restrict__ WK,
    const float* __restrict__ avec, const float* __restrict__ W2,
    const float* __restrict__ b2, float* __restrict__ Wc, float* __restrict__ bc,
    const float* __restrict__ rbf, const float* __restrict__ W1,
    const float* __restrict__ b1, unsigned short* __restrict__ h1)
{
    __shared__ __align__(16) char smem[16896];
    int tid = threadIdx.x;
    int bx = blockIdx.x;
    if (bx < 48) {                       // ---- combined weights (wc) ----
        float* w2s = (float*)smem;              // [64][16]
        float* wsm = (float*)(smem + 4096);     // [16][16]
        float* as  = (float*)(smem + 5120);     // [16]
        float* b2s = (float*)(smem + 5184);     // [16]
        int side = bx / NDH, dh = bx % NDH;
        int d = dh >> 3, h = dh & 7;
        int colbase = d * 256 + h * 32 + side * 16;
        const float* W = (side == 0) ? WQ : WK;
        for (int e = tid; e < 1024; e += 256)
            w2s[e] = W2[(e >> 4) * FILT_OUT + colbase + (e & 15)];
        wsm[tid] = W[((d * 8 + h) * 16) * 16 + tid];
        if (tid < 16) { as[tid] = avec[dh * 32 + side * 16 + tid]; b2s[tid] = b2[colbase + tid]; }
        __syncthreads();
        for (int o = tid; o < 1024; o += 256) {
            int k = o >> 4, j = o & 15;
            float s = 0.f;
            #pragma unroll
            for (int c = 0; c < 16; ++c) s += w2s[k * 16 + c] * as[c] * wsm[c * 16 + j];
            Wc[((size_t)bx * 64 + k) * 16 + j] = s;
        }
        if (tid < 16) {
            float s = 0.f;
            #pragma unroll
            for (int c = 0; c < 16; ++c) s += b2s[c] * as[c] * wsm[c * 16 + tid];
            bc[bx * 16 + tid] = s;
        }
        return;
    }
    bx -= 48;
    if (bx < 512) {                      // ---- segment starts (idx_i sorted) ----
        int p = bx * 256 + tid;
        int ii = idx_i[p];
        int prev = (p == 0) ? -1 : idx_i[p - 1];
        for (int a = prev + 1; a <= ii; ++a) row_start[a] = p;
        if (p == N_PAIR - 1) {
            for (int a = ii + 1; a <= N_ATOMS; ++a) row_start[a] = N_PAIR;
        }
        return;
    }
    bx -= 512;
    if (bx < 512) {                      // ---- histogram of idx_j ----
        int p = bx * 256 + tid;
        atomicAdd(&counts[idx_j[p]], 1);
        return;
    }
    bx -= 512;
    {                                    // ---- h1 = silu(rbf @ W1 + b1) ----
        float* w1s  = (float*)smem;             // [32][64]
        float* b1s  = (float*)(smem + 8192);    // [64]
        float* rbfs = (float*)(smem + 8448);    // [64][33]
        int p0 = bx * 64;
        for (int e = tid; e < K_RBF * H_FILT; e += 256) w1s[e] = W1[e];
        if (tid < H_FILT) b1s[tid] = b1[tid];
        for (int e = tid; e < 64 * K_RBF; e += 256)
            rbfs[(e >> 5) * 33 + (e & 31)] = rbf[(size_t)p0 * K_RBF + e];
        __syncthreads();
        int pp = tid >> 2;
        int kbase = (tid & 3) * 16;
        float acc[16];
        #pragma unroll
        for (int q = 0; q < 16; ++q) acc[q] = b1s[kbase + q];
        for (int c = 0; c < K_RBF; ++c) {
            float r = rbfs[pp * 33 + c];
            #pragma unroll
            for (int q = 0; q < 16; ++q) acc[q] += r * w1s[c * 64 + kbase + q];
        }
        u16x8 o0, o1;
        #pragma unroll
        for (int q = 0; q < 8; ++q) {
            float s0 = acc[q];     o0[q] = f2bfbits(s0 / (1.f + __expf(-s0)));
            float s1 = acc[q + 8]; o1[q] = f2bfbits(s1 / (1.f + __expf(-s1)));
        }
        unsigned short* hp = h1 + (size_t)(p0 + pp) * 64 + kbase;
        *reinterpret_cast<u16x8*>(hp) = o0;
        *reinterpret_cast<u16x8*>(hp + 8) = o1;
    }
}

// ---------------- exclusive scan of 8192 counts (1 block) ----------------
__global__ __launch_bounds__(1024) void k_scan(const int* __restrict__ counts,
                                               int* __restrict__ offsets) {
    __shared__ int ts[1024];
    int tid = threadIdx.x;
    int base = tid * 8;
    int v[8]; int tot = 0;
    #pragma unroll
    for (int q = 0; q < 8; ++q) { v[q] = counts[base + q]; tot += v[q]; }
    ts[tid] = tot; __syncthreads();
    for (int off = 1; off < 1024; off <<= 1) {
        int t2 = (tid >= off) ? ts[tid - off] : 0;
        __syncthreads();
        ts[tid] += t2;
        __syncthreads();
    }
    int excl = ts[tid] - tot;
    #pragma unroll
    for (int q = 0; q < 8; ++q) { offsets[base + q] = excl; excl += v[q]; }
    if (tid == 1023) offsets[N_ATOMS] = ts[1023];
}

// ---------------- placement: sorted pair ids per j-bucket + rank ----------------
__global__ void k_place(const int* __restrict__ idx_j, const int* __restrict__ offsets,
                        int* __restrict__ cnt2, int* __restrict__ sorted,
                        int* __restrict__ rank) {
    int p = blockIdx.x * 256 + threadIdx.x;
    if (p < N_PAIR) {
        int j = idx_j[p];
        int pos = offsets[j] + atomicAdd(&cnt2[j], 1);
        sorted[pos] = p;
        rank[p] = pos;
    }
}

// ---------------- K_gfused: x -> Gq/Gk/bq/bk directly ----------------
__global__ __launch_bounds__(256) void k_gfused(
    const float* __restrict__ x, const float* __restrict__ Wc,
    const float* __restrict__ bc,
    __hip_bfloat16* __restrict__ Gq, __hip_bfloat16* __restrict__ Gk,
    float* __restrict__ bq, float* __restrict__ bk)
{
    int bx = blockIdx.x;             // 128 blocks of 64 atoms
    int by = blockIdx.y;             // 0..47: side, dh
    int side = by / NDH, dh = by % NDH;
    int h = dh & 7;
    int n0 = bx * 64;
    __shared__ float xh[64][17];     // padded: conflict-free per-at reads
    __shared__ float bcs[16];
    int tid = threadIdx.x;
    for (int e = tid; e < 64 * 16; e += 256)
        xh[e >> 4][e & 15] = x[(size_t)(n0 + (e >> 4)) * F + h * 16 + (e & 15)];
    if (tid < 16) bcs[tid] = bc[by * 16 + tid];
    int k = tid & 63, wv = tid >> 6;
    float wcr[16];
    const float* wp = Wc + ((size_t)by * 64 + k) * 16;
    #pragma unroll
    for (int j = 0; j < 16; ++j) wcr[j] = wp[j];
    __syncthreads();
    __hip_bfloat16* G = (side == 0) ? Gq : Gk;
    #pragma unroll 4
    for (int it = 0; it < 16; ++it) {
        int at = wv * 16 + it;
        float acc = 0.f;
        #pragma unroll
        for (int j = 0; j < 16; ++j) acc += wcr[j] * xh[at][j];  // broadcast reads
        G[(size_t)(n0 + at) * 1536 + dh * 64 + k] = __float2bfloat16(acc);
    }
    if (tid < 64) {
        float* B = (side == 0) ? bq : bk;
        float s = 0.f;
        #pragma unroll
        for (int j = 0; j < 16; ++j) s += bcs[j] * xh[tid][j];
        B[(n0 + tid) * NDH + dh] = s;
    }
}

#if !HAVE_BF16_DOT2
// ------- fallback helpers: f32 LDS staging + manual unpack dot -------
__device__ __forceinline__ void stage_h1f(float (*h1f)[72],
                                          const unsigned short* __restrict__ h1,
                                          const int* ps, int tid) {
    for (int e = tid; e < 64 * 32; e += 256) {
        int slot = e >> 5, kp = e & 31;
        unsigned d = *reinterpret_cast<const unsigned*>(h1 + (size_t)ps[slot] * 64 + kp * 2);
        float2 f;
        f.x = __uint_as_float(d << 16);
        f.y = __uint_as_float(d & 0xFFFF0000u);
        *reinterpret_cast<float2*>(&h1f[slot][kp * 2]) = f;
    }
}
__device__ __forceinline__ float dot8u(uint4 g, float4 h0, float4 h1v) {
    float p;
    p  = __uint_as_float(g.x << 16) * h0.x + __uint_as_float(g.x & 0xFFFF0000u) * h0.y;
    p += __uint_as_float(g.y << 16) * h0.z + __uint_as_float(g.y & 0xFFFF0000u) * h0.w;
    p += __uint_as_float(g.z << 16) * h1v.x + __uint_as_float(g.z & 0xFFFF0000u) * h1v.y;
    p += __uint_as_float(g.w << 16) * h1v.z + __uint_as_float(g.w & 0xFFFF0000u) * h1v.w;
    return p;
}
#endif

// ---------------- K2c: K-side alpha, seg-parallel, 4-wide ILP ----------------
__global__ __launch_bounds__(256) void k_alphak3(
    const int* __restrict__ sorted, const int* __restrict__ idx_j,
    const unsigned short* __restrict__ h1,
    const __hip_bfloat16* __restrict__ Gk, const float* __restrict__ bk,
    unsigned short* __restrict__ alphaKs)
{
#if HAVE_BF16_DOT2
    __shared__ __align__(16) unsigned short h1s[64][72]; // 9 KB
#else
    __shared__ __align__(16) float h1f[64][72];          // 18 KB
#endif
    __shared__ float als[64][24];
    __shared__ int ps[64];
    __shared__ int js[64];
    int tid = threadIdx.x;
    int c0 = blockIdx.x * 64;
    if (tid < 64) {
        int pid = sorted[c0 + tid];
        ps[tid] = pid;
        js[tid] = idx_j[pid];
    }
    __syncthreads();
#if HAVE_BF16_DOT2
    for (int e = tid; e < 64 * 8; e += 256) {
        int slot = e >> 3, seg = e & 7;
        *reinterpret_cast<u16x8*>(&h1s[slot][seg * 8]) =
            *reinterpret_cast<const u16x8*>(h1 + (size_t)ps[slot] * 64 + seg * 8);
    }
#else
    stage_h1f(h1f, h1, ps, tid);
#endif
    __syncthreads();
    const unsigned short* GkU = reinterpret_cast<const unsigned short*>(Gk);
    int seg = tid & 7;
    for (int t = 0; t < 12; ++t) {
        int base = t * 1024 + tid;
        int ds0 = base >> 3, ds1 = (base + 256) >> 3,
            ds2 = (base + 512) >> 3, ds3 = (base + 768) >> 3;
        int s0 = ds0 / 24, d0 = ds0 - s0 * 24;
        int s1 = ds1 / 24, d1 = ds1 - s1 * 24;
        int s2 = ds2 / 24, d2 = ds2 - s2 * 24;
        int s3 = ds3 / 24, d3 = ds3 - s3 * 24;
        uint4 g0 = *reinterpret_cast<const uint4*>(GkU + (size_t)js[s0] * 1536 + d0 * 64 + seg * 8);
        uint4 g1 = *reinterpret_cast<const uint4*>(GkU + (size_t)js[s1] * 1536 + d1 * 64 + seg * 8);
        uint4 g2 = *reinterpret_cast<const uint4*>(GkU + (size_t)js[s2] * 1536 + d2 * 64 + seg * 8);
        uint4 g3 = *reinterpret_cast<const uint4*>(GkU + (size_t)js[s3] * 1536 + d3 * 64 + seg * 8);
#if HAVE_BF16_DOT2
        uint4 h0 = *reinterpret_cast<const uint4*>(&h1s[s0][seg * 8]);
        uint4 h1q = *reinterpret_cast<const uint4*>(&h1s[s1][seg * 8]);
        uint4 h2 = *reinterpret_cast<const uint4*>(&h1s[s2][seg * 8]);
        uint4 h3 = *reinterpret_cast<const uint4*>(&h1s[s3][seg * 8]);
        float p0 = dot8d(g0, h0, 0.f);
        float p1 = dot8d(g1, h1q, 0.f);
        float p2 = dot8d(g2, h2, 0.f);
        float p3 = dot8d(g3, h3, 0.f);
#else
        float p0 = dot8u(g0, *reinterpret_cast<const float4*>(&h1f[s0][seg * 8]),
                             *reinterpret_cast<const float4*>(&h1f[s0][seg * 8 + 4]));
        float p1 = dot8u(g1, *reinterpret_cast<const float4*>(&h1f[s1][seg * 8]),
                             *reinterpret_cast<const float4*>(&h1f[s1][seg * 8 + 4]));
        float p2 = dot8u(g2, *reinterpret_cast<const float4*>(&h1f[s2][seg * 8]),
                             *reinterpret_cast<const float4*>(&h1f[s2][seg * 8 + 4]));
        float p3 = dot8u(g3, *reinterpret_cast<const float4*>(&h1f[s3][seg * 8]),
                             *reinterpret_cast<const float4*>(&h1f[s3][seg * 8 + 4]));
#endif
        p0 += __shfl_xor(p0, 1); p1 += __shfl_xor(p1, 1);
        p2 += __shfl_xor(p2, 1); p3 += __shfl_xor(p3, 1);
        p0 += __shfl_xor(p0, 2); p1 += __shfl_xor(p1, 2);
        p2 += __shfl_xor(p2, 2); p3 += __shfl_xor(p3, 2);
        p0 += __shfl_xor(p0, 4); p1 += __shfl_xor(p1, 4);
        p2 += __shfl_xor(p2, 4); p3 += __shfl_xor(p3, 4);
        if (seg == 0) {
            als[s0][d0] = p0; als[s1][d1] = p1;
            als[s2][d2] = p2; als[s3][d3] = p3;
        }
    }
    __syncthreads();
    for (int e = tid; e < 64 * 24; e += 256) {
        int slot = e / 24, dh = e - slot * 24;
        float val = als[slot][dh] + bk[js[slot] * NDH + dh];
        alphaKs[(size_t)c0 * 24 + e] = f2bfbits(val);
    }
}

// ---------------- K2d: full alpha in p-order, seg-parallel, 4-wide ILP ----------------
// alphaF = (dotQ + bq + alphaKs[rank]) * phi * mask^2 * 0.25
__global__ __launch_bounds__(256) void k_alphaA3(
    const int* __restrict__ idx_i, const int* __restrict__ rank,
    const float* __restrict__ phi, const float* __restrict__ mask,
    const unsigned short* __restrict__ h1,
    const __hip_bfloat16* __restrict__ Gq, const float* __restrict__ bq,
    const unsigned short* __restrict__ alphaKs,
    float* __restrict__ alphaF)
{
#if HAVE_BF16_DOT2
    __shared__ __align__(16) unsigned short h1s[64][72];
#else
    __shared__ __align__(16) float h1f[64][72];
#endif
    __shared__ float als[64][24];
    __shared__ int is[64];
    __shared__ int rks[64];
    __shared__ float pms[64];
#if !HAVE_BF16_DOT2
    __shared__ int psn[64];
#endif
    int tid = threadIdx.x;
    int p0 = blockIdx.x * 64;
    if (tid < 64) {
        int p = p0 + tid;
        is[tid] = idx_i[p];
        rks[tid] = rank[p];
        float mk = mask[p];
        pms[tid] = phi[p] * mk * mk * 0.25f;
#if !HAVE_BF16_DOT2
        psn[tid] = p;
#endif
    }
    __syncthreads();
#if HAVE_BF16_DOT2
    for (int e = tid; e < 64 * 8; e += 256) {
        int slot = e >> 3, seg = e & 7;
        *reinterpret_cast<u16x8*>(&h1s[slot][seg * 8]) =
            *reinterpret_cast<const u16x8*>(h1 + (size_t)(p0 + slot) * 64 + seg * 8);
    }
#else
    stage_h1f(h1f, h1, psn, tid);
#endif
    __syncthreads();
    const unsigned short* GqU = reinterpret_cast<const unsigned short*>(Gq);
    int seg = tid & 7;
    for (int t = 0; t < 12; ++t) {
        int base = t * 1024 + tid;
        int ds0 = base >> 3, ds1 = (base + 256) >> 3,
            ds2 = (base + 512) >> 3, ds3 = (base + 768) >> 3;
        int s0 = ds0 / 24, d0 = ds0 - s0 * 24;
        int s1 = ds1 / 24, d1 = ds1 - s1 * 24;
        int s2 = ds2 / 24, d2 = ds2 - s2 * 24;
        int s3 = ds3 / 24, d3 = ds3 - s3 * 24;
        uint4 g0 = *reinterpret_cast<const uint4*>(GqU + (size_t)is[s0] * 1536 + d0 * 64 + seg * 8);
        uint4 g1 = *reinterpret_cast<const uint4*>(GqU + (size_t)is[s1] * 1536 + d1 * 64 + seg * 8);
        uint4 g2 = *reinterpret_cast<const uint4*>(GqU + (size_t)is[s2] * 1536 + d2 * 64 + seg * 8);
        uint4 g3 = *reinterpret_cast<const uint4*>(GqU + (size_t)is[s3] * 1536 + d3 * 64 + seg * 8);
#if HAVE_BF16_DOT2
        uint4 h0 = *reinterpret_cast<const uint4*>(&h1s[s0][seg * 8]);
        uint4 h1q = *reinterpret_cast<const uint4*>(&h1s[s1][seg * 8]);
        uint4 h2 = *reinterpret_cast<const uint4*>(&h1s[s2][seg * 8]);
        uint4 h3 = *reinterpret_cast<const uint4*>(&h1s[s3][seg * 8]);
        float p0v = dot8d(g0, h0, 0.f);
        float p1v = dot8d(g1, h1q, 0.f);
        float p2v = dot8d(g2, h2, 0.f);
        float p3v = dot8d(g3, h3, 0.f);
#else
        float p0v = dot8u(g0, *reinterpret_cast<const float4*>(&h1f[s0][seg * 8]),
                              *reinterpret_cast<const float4*>(&h1f[s0][seg * 8 + 4]));
        float p1v = dot8u(g1, *reinterpret_cast<const float4*>(&h1f[s1][seg * 8]),
                              *reinterpret_cast<const float4*>(&h1f[s1][seg * 8 + 4]));
        float p2v = dot8u(g2, *reinterpret_cast<const float4*>(&h1f[s2][seg * 8]),
                              *reinterpret_cast<const float4*>(&h1f[s2][seg * 8 + 4]));
        float p3v = dot8u(g3, *reinterpret_cast<const float4*>(&h1f[s3][seg * 8]),
                              *reinterpret_cast<const float4*>(&h1f[s3][seg * 8 + 4]));
#endif
        p0v += __shfl_xor(p0v, 1); p1v += __shfl_xor(p1v, 1);
        p2v += __shfl_xor(p2v, 1); p3v += __shfl_xor(p3v, 1);
        p0v += __shfl_xor(p0v, 2); p1v += __shfl_xor(p1v, 2);
        p2v += __shfl_xor(p2v, 2); p3v += __shfl_xor(p3v, 2);
        p0v += __shfl_xor(p0v, 4); p1v += __shfl_xor(p1v, 4);
        p2v += __shfl_xor(p2v, 4); p3v += __shfl_xor(p3v, 4);
        if (seg == 0) {
            als[s0][d0] = p0v; als[s1][d1] = p1v;
            als[s2][d2] = p2v; als[s3][d3] = p3v;
        }
    }
    __syncthreads();
    for (int e = tid; e < 64 * 24; e += 256) {
        int slot = e / 24, dh = e - slot * 24;
        float val = als[slot][dh] + bq[is[slot] * NDH + dh]
                  + bf2f(alphaKs[(size_t)rks[slot] * 24 + dh]);
        alphaF[(size_t)p0 * 24 + e] = val * pms[slot];
    }
}

// ---------------- K3: segment-sum, 2 atoms/block (grid 4096), transposed als ----------------
__global__ __launch_bounds__(256) void k_aggr9(
    const float* __restrict__ x, const float* __restrict__ sph,
    const int* __restrict__ idx_i, const int* __restrict__ idx_j,
    const float* __restrict__ alphaF,
    const int* __restrict__ row_start, float* __restrict__ out)
{
    int a0 = blockIdx.x * ATB;
    int tid = threadIdx.x;
    int f = tid & 127, grp = tid >> 7, h = f >> 4;

    __shared__ float alsT[64][8][4];  // 8 KB: [q][h][d] (d=0,1,2 + pad)
    __shared__ float sls[64][16];     // 4 KB (padded)
    __shared__ int   iis[64];
    __shared__ int   jjs[64];
    __shared__ int   rs[ATB + 1];

    if (tid <= ATB) rs[tid] = row_start[a0 + tid];
    __syncthreads();
    int pstart = rs[0], pend = rs[ATB];

    float acc[8];
    #pragma unroll
    for (int m = 0; m < 8; ++m) acc[m] = 0.f;
    int cur = -1;

#define FLUSH(CUR)                                                        \
    { size_t ob = (size_t)(CUR) * (M_TOT * F) + f;                        \
      if (grp == 0) {                                                     \
          _Pragma("unroll")                                               \
          for (int m = 0; m < 8; ++m) out[ob + m * 128] = acc[m];         \
      } else {                                                            \
          _Pragma("unroll")                                               \
          for (int m = 0; m < 7; ++m) out[ob + (8 + m) * 128] = acc[m];   \
      } }

#define AGG_STEP(Q, XV)                                                   \
    { int ia = iis[Q];                                                    \
      if (ia != cur) {                                                    \
          if (cur >= 0) FLUSH(cur);                                       \
          cur = ia;                                                       \
          _Pragma("unroll")                                               \
          for (int m = 0; m < 8; ++m) acc[m] = 0.f;                       \
      }                                                                   \
      if (grp == 0) {                                                     \
          float2 t01 = *reinterpret_cast<const float2*>(&alsT[Q][h][0]);  \
          float t0 = t01.x * (XV);                                        \
          float t1 = t01.y * (XV);                                        \
          acc[0] += t0 * sls[Q][0];                                       \
          acc[1] += t0 * sls[Q][1];                                       \
          acc[2] += t0 * sls[Q][2];                                       \
          _Pragma("unroll")                                               \
          for (int m = 3; m < 8; ++m) acc[m] += t1 * sls[Q][m];           \
      } else {                                                            \
          float t2 = alsT[Q][h][2] * (XV);                                \
          _Pragma("unroll")                                               \
          for (int m = 0; m < 7; ++m) acc[m] += t2 * sls[Q][8 + m];       \
      } }

    for (int pc = pstart; pc < pend; pc += 64) {
        int nb = min(64, pend - pc);
        __syncthreads();
        if (tid < nb) {
            int p = pc + tid;
            iis[tid] = idx_i[p];
            jjs[tid] = idx_j[p];
        }
        for (int e = tid; e < nb * 24; e += 256) {
            int q = e / 24, dh = e - q * 24;
            alsT[q][dh & 7][dh >> 3] = alphaF[(size_t)pc * 24 + e];
        }
        for (int e = tid; e < nb * 15; e += 256)
            sls[e / 15][e % 15] = sph[(size_t)pc * 15 + e];
        __syncthreads();
        float xa = 0.f, xb = 0.f, xc = 0.f, xd = 0.f;
        if (nb > 0) xa = x[(size_t)jjs[0] * F + f];
        if (nb > 1) xb = x[(size_t)jjs[1] * F + f];
        if (nb > 2) xc = x[(size_t)jjs[2] * F + f];
        if (nb > 3) xd = x[(size_t)jjs[3] * F + f];
        for (int qg = 0; qg < nb; qg += 4) {
            float ya = 0.f, yb = 0.f, yc = 0.f, yd = 0.f;
            int nq = qg + 4;
            if (nq < nb) {
                ya = x[(size_t)jjs[nq] * F + f];
                if (nq + 1 < nb) yb = x[(size_t)jjs[nq + 1] * F + f];
                if (nq + 2 < nb) yc = x[(size_t)jjs[nq + 2] * F + f];
                if (nq + 3 < nb) yd = x[(size_t)jjs[nq + 3] * F + f];
            }
            AGG_STEP(qg, xa);
            if (qg + 1 < nb) AGG_STEP(qg + 1, xb);
            if (qg + 2 < nb) AGG_STEP(qg + 2, xc);
            if (qg + 3 < nb) AGG_STEP(qg + 3, xd);
            xa = ya; xb = yb; xc = yc; xd = yd;
        }
    }
    if (cur >= 0) FLUSH(cur);
    // zero-fill atoms with no pairs
    for (int a = 0; a < ATB; ++a) {
        if (rs[a] == rs[a + 1]) {
            size_t ob = (size_t)(a0 + a) * (M_TOT * F) + f;
            if (grp == 0) {
                #pragma unroll
                for (int m = 0; m < 8; ++m) out[ob + m * 128] = 0.f;
            } else {
                #pragma unroll
                for (int m = 0; m < 7; ++m) out[ob + (8 + m) * 128] = 0.f;
            }
        }
    }
#undef AGG_STEP
#undef FLUSH
}

extern "C" void kernel_launch(void* const* d_in, const int* in_sizes, int n_in,
                              void* d_out, int out_size, void* d_ws, size_t ws_size,
                              hipStream_t stream) {
    const float* x     = (const float*)d_in[0];
    const float* rbf   = (const float*)d_in[1];
    const float* sph   = (const float*)d_in[2];
    const float* phi   = (const float*)d_in[3];
    const int*   idx_i = (const int*)d_in[4];
    const int*   idx_j = (const int*)d_in[5];
    const float* mask  = (const float*)d_in[6];
    const float* WQ    = (const float*)d_in[7];
    const float* WK    = (const float*)d_in[8];
    const float* av    = (const float*)d_in[9];
    const float* W1    = (const float*)d_in[10];
    const float* b1    = (const float*)d_in[11];
    const float* W2    = (const float*)d_in[12];
    const float* b2    = (const float*)d_in[13];
    float* out = (float*)d_out;
    char* ws = (char*)d_ws;

    // ws layout (bytes): identical to R15-R17
    __hip_bfloat16* Gq = (__hip_bfloat16*)(ws + 0);
    __hip_bfloat16* Gk = (__hip_bfloat16*)(ws + 25165824);
    float* alphaF = (float*)(ws + 25165824);       // aliases Gk (dead after k_alphak3)
    float* bq = (float*)(ws + 50331648);
    float* bk = (float*)(ws + 51118080);
    int* row_start = (int*)(ws + 51904512);
    int* counts    = (int*)(ws + 51937792);
    int* cnt2      = (int*)(ws + 51970560);
    int* offsets   = (int*)(ws + 52003328);
    int* sorted    = (int*)(ws + 52036608);
    int* rank      = (int*)(ws + 52560896);
    unsigned short* h1      = (unsigned short*)(ws + 53085184);
    unsigned short* alphaKs = (unsigned short*)(ws + 69862400);
    float* Wc = (float*)(ws + 76153856);
    float* bc = (float*)(ws + 76350464);

    hipMemsetAsync(ws + 51937792, 0, 65536, stream);
    // k_front: [0,48)=wc | [48,560)=seg | [560,1072)=hist | [1072,3120)=h1
    k_front<<<3120, 256, 0, stream>>>(idx_i, idx_j, row_start, counts,
                                      WQ, WK, av, W2, b2, Wc, bc,
                                      rbf, W1, b1, h1);
    k_scan<<<1, 1024, 0, stream>>>(counts, offsets);
    k_place<<<(N_PAIR + 255) / 256, 256, 0, stream>>>(idx_j, offsets, cnt2, sorted, rank);
    k_gfused<<<dim3(N_ATOMS / 64, 48), 256, 0, stream>>>(x, Wc, bc, Gq, Gk, bq, bk);
    k_alphak3<<<N_PAIR / 64, 256, 0, stream>>>(sorted, idx_j, h1, Gk, bk, alphaKs);
    k_alphaA3<<<N_PAIR / 64, 256, 0, stream>>>(idx_i, rank, phi, mask, h1, Gq, bq,
                                               alphaKs, alphaF);
    k_aggr9<<<N_ATOMS / ATB, 256, 0, stream>>>(x, sph, idx_i, idx_j, alphaF,
                                               row_start, out);
}